// Round 1
// 62.146 us; speedup vs baseline: 1.0323x; 1.0323x over previous
//
#include <hip/hip_runtime.h>

constexpr int SEQ_LEN = 200;
constexpr int BATCH   = 4096;
constexpr int V       = 50000;

constexpr int DOCS    = 8;                  // docs per block
constexpr int NTHR    = 1024;               // 16 waves/block, 2 blocks/CU -> 8 waves/SIMD
constexpr int SLICES  = NTHR / DOCS;        // 128 token-slices per doc
constexpr int WAVES   = NTHR / 64;          // 16
// per-doc bitset: ceil(50000/32)=1563 words; pad to 1568 (%4==0 for uint4 init,
// %32==0 so bank = word_index & 31 -> uniform banks for random tokens)
constexpr int BITWPAD = 1568;

__global__ __launch_bounds__(NTHR, 8) void MNB_8151847928093_kernel(
    const int*   __restrict__ text,   // [SEQ_LEN, BATCH]
    const float* __restrict__ W,      // [V]
    const float* __restrict__ bias,   // [1]
    float*       __restrict__ out)    // [BATCH]
{
    __shared__ __align__(16) unsigned bits[DOCS * BITWPAD];  // 50,176 B
    __shared__ float psum[WAVES * DOCS];                     // 512 B

    const int tid   = threadIdx.x;
    const int doc   = tid & (DOCS - 1);
    const int slice = tid >> 3;                              // 0..127
    const int b     = blockIdx.x * DOCS + doc;

    // zero the bitsets with 16B stores
    uint4* bv = reinterpret_cast<uint4*>(bits);
    for (int i = tid; i < DOCS * BITWPAD / 4; i += NTHR)
        bv[i] = make_uint4(0u, 0u, 0u, 0u);
    __syncthreads();

    // two tokens per thread; second only for slice<72 (wave-uniform guard).
    // Invalid lanes re-load their own t0 row (t1==t0) so the unguarded load
    // and gather are always safe and stay hoisted above the atomics.
    const bool v1 = slice < (SEQ_LEN - SLICES);              // slice < 72
    const int  r1 = v1 ? slice + SLICES : slice;

    const unsigned t0 = (unsigned)text[slice * BATCH + b];
    const unsigned t1 = (unsigned)text[r1 * BATCH + b];
    const float    w0 = W[t0];
    const float    w1 = W[t1];

    unsigned* const base = bits + doc * BITWPAD;

    const unsigned o0 = atomicOr(base + (t0 >> 5), 1u << (t0 & 31u));
    float sum = ((o0 >> (t0 & 31u)) & 1u) ? 0.0f : w0;
    if (v1) {                                                // wave-uniform
        const unsigned o1 = atomicOr(base + (t1 >> 5), 1u << (t1 & 31u));
        sum += ((o1 >> (t1 & 31u)) & 1u) ? 0.0f : w1;
    }

    // reduce the 8 lanes of each doc within the wave (lane ≡ doc mod 8)
    sum += __shfl_xor(sum, 8, 64);
    sum += __shfl_xor(sum, 16, 64);
    sum += __shfl_xor(sum, 32, 64);

    const int wave = tid >> 6;
    const int lane = tid & 63;
    if (lane < DOCS) psum[wave * DOCS + lane] = sum;
    __syncthreads();

    if (tid < DOCS) {
        float s = bias[0];
        #pragma unroll
        for (int k = 0; k < WAVES; ++k) s += psum[k * DOCS + tid];
        out[blockIdx.x * DOCS + tid] = s;
    }
}

extern "C" void kernel_launch(void* const* d_in, const int* in_sizes, int n_in,
                              void* d_out, int out_size, void* d_ws, size_t ws_size,
                              hipStream_t stream) {
    const int*   text = (const int*)d_in[0];
    const float* W    = (const float*)d_in[1];
    const float* bias = (const float*)d_in[2];
    float*       out  = (float*)d_out;

    MNB_8151847928093_kernel<<<BATCH / DOCS, NTHR, 0, stream>>>(text, W, bias, out);
}

// Round 2
// 61.887 us; speedup vs baseline: 1.0366x; 1.0042x over previous
//
#include <hip/hip_runtime.h>

constexpr int SEQ_LEN = 200;
constexpr int BATCH   = 4096;
constexpr int V       = 50000;

constexpr int DOCS    = 8;                  // docs per block
constexpr int NTHR    = 1024;               // 16 waves/block, 2 blocks/CU -> 8 waves/SIMD
constexpr int SLICES  = NTHR / DOCS;        // 128 token-slices per doc
constexpr int WAVES   = NTHR / 64;          // 16
// per-doc bitset: ceil(50000/32)=1563 words; pad to 1568 (%4==0 for uint4 init,
// %32==0 so bank = word_index & 31 -> uniform banks for random tokens)
constexpr int BITWPAD = 1568;

__global__ __launch_bounds__(NTHR, 8) void MNB_8151847928093_kernel(
    const int*   __restrict__ text,   // [SEQ_LEN, BATCH]
    const float* __restrict__ W,      // [V]
    const float* __restrict__ bias,   // [1]
    float*       __restrict__ out)    // [BATCH]
{
    __shared__ __align__(16) unsigned bits[DOCS * BITWPAD];  // 50,176 B
    __shared__ float psum[WAVES * DOCS];                     // 512 B

    const int tid   = threadIdx.x;
    const int doc   = tid & (DOCS - 1);
    const int slice = tid >> 3;                              // 0..127
    const int b     = blockIdx.x * DOCS + doc;

    // ---- 1) issue token loads FIRST (HBM-cold ~900 cy) ------------------
    // second token only for slice<72 (wave-uniform); invalid lanes reload
    // their own t0 row so the unguarded load/gather are always safe.
    const bool v1 = slice < (SEQ_LEN - SLICES);              // slice < 72
    const int  r1 = v1 ? slice + SLICES : slice;

    const unsigned t0 = (unsigned)text[slice * BATCH + b];
    const unsigned t1 = (unsigned)text[r1 * BATCH + b];

    // ---- 2) zero the bitsets while token loads are in flight ------------
    uint4* bv = reinterpret_cast<uint4*>(bits);
    #pragma unroll
    for (int i = 0; i < DOCS * BITWPAD / (4 * NTHR); ++i)
        bv[tid + i * NTHR] = make_uint4(0u, 0u, 0u, 0u);
    {   // tail: 3136 words / 4 = 784 uint4; 784 = 3*256 + 16 per 1024... 
        // DOCS*BITWPAD/4 = 784 is not a multiple of NTHR/4; handle remainder
        const int done = (DOCS * BITWPAD / (4 * NTHR)) * NTHR;
        const int idx  = done + tid;
        if (idx < DOCS * BITWPAD / 4) bv[idx] = make_uint4(0u, 0u, 0u, 0u);
    }

    // ---- 3) issue W gathers before the barrier: the barrier's vmcnt(0)
    //         drain doubles as the gather wait ---------------------------
    const float w0 = W[t0];
    const float w1 = W[t1];

    __syncthreads();

    // ---- 4) membership via exact bitset: one atomicOr per token ---------
    unsigned* const base = bits + doc * BITWPAD;

    const unsigned o0 = atomicOr(base + (t0 >> 5), 1u << (t0 & 31u));
    float sum = ((o0 >> (t0 & 31u)) & 1u) ? 0.0f : w0;
    if (v1) {                                                // wave-uniform
        const unsigned o1 = atomicOr(base + (t1 >> 5), 1u << (t1 & 31u));
        sum += ((o1 >> (t1 & 31u)) & 1u) ? 0.0f : w1;
    }

    // ---- 5) reduce the 8 lanes of each doc within the wave --------------
    sum += __shfl_xor(sum, 8, 64);
    sum += __shfl_xor(sum, 16, 64);
    sum += __shfl_xor(sum, 32, 64);

    const int wave = tid >> 6;
    const int lane = tid & 63;
    if (lane < DOCS) psum[wave * DOCS + lane] = sum;
    __syncthreads();

    if (tid < DOCS) {
        float s = bias[0];
        #pragma unroll
        for (int k = 0; k < WAVES; ++k) s += psum[k * DOCS + tid];
        out[blockIdx.x * DOCS + tid] = s;
    }
}

extern "C" void kernel_launch(void* const* d_in, const int* in_sizes, int n_in,
                              void* d_out, int out_size, void* d_ws, size_t ws_size,
                              hipStream_t stream) {
    const int*   text = (const int*)d_in[0];
    const float* W    = (const float*)d_in[1];
    const float* bias = (const float*)d_in[2];
    float*       out  = (float*)d_out;

    MNB_8151847928093_kernel<<<BATCH / DOCS, NTHR, 0, stream>>>(text, W, bias, out);
}